// Round 12
// baseline (197.711 us; speedup 1.0000x reference)
//
#include <hip/hip_runtime.h>
#include <hip/hip_bf16.h>

// Resonance tiling via fused block-GEMM on MFMA — barrier-free streaming v3.
// Math: per tile t, [y1,y2] = [x1,x2] * M_t, M_t = [[I,Psi],[Phi,I+Phi*Psi]]
// (128x128 bf16, built once by prep_kernel into d_ws).
//
// Round-11 lessons: (a) still miss-limited — 8 loads in flight/wave, wave
// blocks after ~250cyc work; (b) nontemporal stores bypassed L2 write
// coalescing (WRITE 262->322MB). This round:
//  - slim waves: 16 rows x 32 n-cols (a-frags 32 VGPR, 8 MFMA) -> block =
//    4 waves sharing the same 16 rows (L1 absorbs), ~130 real VGPR.
//  - 2-deep prefetch: LA/LB named buffers, 2-phase unrolled loop -> cvt
//    waits on loads issued TWO iterations back.
//  - plain stores (no nt), loads still issued before stores (vmcnt order).

typedef __attribute__((ext_vector_type(8))) short bf16x8;
typedef __attribute__((ext_vector_type(4))) float f32x4;

static __device__ __forceinline__ unsigned short f2bf(float f) {
    unsigned u = __builtin_bit_cast(unsigned, f);
    unsigned r = 0x7FFFu + ((u >> 16) & 1u);     // round-to-nearest-even
    return (unsigned short)((u + r) >> 16);
}

static __device__ __forceinline__ short hwbf(float f) {
    __hip_bfloat16 h = __float2bfloat16(f);       // hardware v_cvt
    return __builtin_bit_cast(short, h);
}

// ---------------- pre-kernel: build M_t^T (bf16) ----------------
__global__ __launch_bounds__(256)
void prep_kernel(const float4* __restrict__ phi,
                 const float4* __restrict__ psi,
                 unsigned short* __restrict__ mt) {
    __shared__ float Phi[64][64];
    __shared__ float Psi[64][64];
    const int t   = blockIdx.x;          // 0..7
    const int tid = threadIdx.x;
    const int i   = tid >> 4, j = tid & 15;

    {   // Hamilton 4x4 block (row-vec convention, matches reference)
        float4 w = phi[t * 256 + i * 16 + j];
        float a = w.x, b = w.y, c = w.z, d = w.w;
        Phi[4*i+0][4*j+0]= a; Phi[4*i+0][4*j+1]= b; Phi[4*i+0][4*j+2]= c; Phi[4*i+0][4*j+3]= d;
        Phi[4*i+1][4*j+0]=-b; Phi[4*i+1][4*j+1]= a; Phi[4*i+1][4*j+2]=-d; Phi[4*i+1][4*j+3]= c;
        Phi[4*i+2][4*j+0]=-c; Phi[4*i+2][4*j+1]= d; Phi[4*i+2][4*j+2]= a; Phi[4*i+2][4*j+3]=-b;
        Phi[4*i+3][4*j+0]=-d; Phi[4*i+3][4*j+1]=-c; Phi[4*i+3][4*j+2]= b; Phi[4*i+3][4*j+3]= a;
        float4 v = psi[(8 + t) * 256 + i * 16 + j];
        a = v.x; b = v.y; c = v.z; d = v.w;
        Psi[4*i+0][4*j+0]= a; Psi[4*i+0][4*j+1]= b; Psi[4*i+0][4*j+2]= c; Psi[4*i+0][4*j+3]= d;
        Psi[4*i+1][4*j+0]=-b; Psi[4*i+1][4*j+1]= a; Psi[4*i+1][4*j+2]=-d; Psi[4*i+1][4*j+3]= c;
        Psi[4*i+2][4*j+0]=-c; Psi[4*i+2][4*j+1]= d; Psi[4*i+2][4*j+2]= a; Psi[4*i+2][4*j+3]=-b;
        Psi[4*i+3][4*j+0]=-d; Psi[4*i+3][4*j+1]=-c; Psi[4*i+3][4*j+2]= b; Psi[4*i+3][4*j+3]= a;
    }
    __syncthreads();

    unsigned short* m = mt + t * 16384;   // MT[n][k] = M[k][n]
    for (int e = tid; e < 16384; e += 256) {
        const int n = e >> 7, k = e & 127;
        if (n >= 64 && k >= 64) continue;
        float v;
        if (k < 64 && n < 64)       v = (k == n) ? 1.f : 0.f;   // M11 = I
        else if (k >= 64)           v = Phi[k - 64][n];          // M21 = Phi
        else                        v = Psi[k][n - 64];          // M12 = Psi
        m[e] = f2bf(v);
    }
    // M22 = I + Phi@Psi
    const int r = tid & 63, c0 = (tid >> 6) * 16;
    float pk[16];
#pragma unroll
    for (int cc = 0; cc < 16; ++cc) pk[cc] = 0.f;
    for (int k = 0; k < 64; ++k) {
        const float fr = Phi[r][k];
#pragma unroll
        for (int cc = 0; cc < 16; ++cc) pk[cc] = fmaf(fr, Psi[k][c0 + cc], pk[cc]);
    }
#pragma unroll
    for (int cc = 0; cc < 16; ++cc) {
        const int c = c0 + cc;
        m[(64 + c) * 128 + (64 + r)] = f2bf(((r == c) ? 1.f : 0.f) + pk[cc]);
    }
}

// ------------- main: barrier-free per-wave streaming GEMM -------------
// wave unit: 16 rows x 32 n-cols (operand-swapped MFMA). block = tile t,
// 4 waves = 4 n-quarters of the SAME 16 rows (L1 reuse). 2-deep prefetch.
__global__ __launch_bounds__(256)
void gemm_kernel(const float* __restrict__ x,
                 const unsigned short* __restrict__ mt,
                 float* __restrict__ out,
                 int ngroups) {
    const int tid  = threadIdx.x;
    const int lane = tid & 63;
    const int wn   = tid >> 6;                 // n-quarter 0..3
    const int ln = lane & 15, lk = lane >> 4;
    const int t  = blockIdx.x & 7;
    const int gs = gridDim.x >> 3;

    // M^T fragments as the A-operand: a[fn][ks] (A row = n, 8 contiguous k)
    bf16x8 a[2][4];
    {
        const unsigned short* mtt = mt + t * 16384;
#pragma unroll
        for (int fn = 0; fn < 2; ++fn)
#pragma unroll
            for (int ks = 0; ks < 4; ++ks)
                a[fn][ks] = *(const bf16x8*)(mtt + (wn * 32 + fn * 16 + ln) * 128
                                                 + ks * 32 + lk * 8);
    }

    const int ca  = t * 64 + lk * 8;   // x f32 col base (+ks offsets)
    // out col base for n = wn*32 + fn*16 + lk*4 (+reg):
    const int cob = t * 64 + ((wn < 2) ? wn * 32 : 512 + (wn - 2) * 32);

    float4 LA[8], LB[8];
#define ISSUE(Lbuf, gg) { \
        const float* xr = x + ((size_t)(gg) * 16 + ln) * 1024 + ca; \
        Lbuf[0] = *(const float4*)(xr + 0);   Lbuf[1] = *(const float4*)(xr + 4); \
        Lbuf[2] = *(const float4*)(xr + 32);  Lbuf[3] = *(const float4*)(xr + 36); \
        Lbuf[4] = *(const float4*)(xr + 512); Lbuf[5] = *(const float4*)(xr + 516); \
        Lbuf[6] = *(const float4*)(xr + 544); Lbuf[7] = *(const float4*)(xr + 548); }

#define PHASE(Lbuf, gg, gpre) { \
        bf16x8 bx[4]; \
        _Pragma("unroll") \
        for (int kk = 0; kk < 4; ++kk) { \
            bx[kk][0] = hwbf(Lbuf[2*kk].x);   bx[kk][1] = hwbf(Lbuf[2*kk].y); \
            bx[kk][2] = hwbf(Lbuf[2*kk].z);   bx[kk][3] = hwbf(Lbuf[2*kk].w); \
            bx[kk][4] = hwbf(Lbuf[2*kk+1].x); bx[kk][5] = hwbf(Lbuf[2*kk+1].y); \
            bx[kk][6] = hwbf(Lbuf[2*kk+1].z); bx[kk][7] = hwbf(Lbuf[2*kk+1].w); \
        } \
        if ((gpre) < ngroups) ISSUE(Lbuf, gpre)          /* loads before stores */ \
        f32x4 acc[2]; \
        acc[0] = (f32x4)(0.f); acc[1] = (f32x4)(0.f); \
        _Pragma("unroll") \
        for (int ks = 0; ks < 4; ++ks) { \
            acc[0] = __builtin_amdgcn_mfma_f32_16x16x32_bf16(a[0][ks], bx[ks], acc[0], 0, 0, 0); \
            acc[1] = __builtin_amdgcn_mfma_f32_16x16x32_bf16(a[1][ks], bx[ks], acc[1], 0, 0, 0); \
        } \
        float* orow = out + ((size_t)(gg) * 16 + ln) * 1024 + cob + lk * 4; \
        *(f32x4*)(orow)      = acc[0]; \
        *(f32x4*)(orow + 16) = acc[1]; }

    int g = blockIdx.x >> 3;
    if (g < ngroups)      ISSUE(LA, g)
    if (g + gs < ngroups) ISSUE(LB, g + gs)

    while (g < ngroups) {
        PHASE(LA, g, g + 2 * gs)
        if (g + gs < ngroups) PHASE(LB, g + gs, g + 3 * gs)
        g += 2 * gs;
    }
#undef PHASE
#undef ISSUE
}

extern "C" void kernel_launch(void* const* d_in, const int* in_sizes, int n_in,
                              void* d_out, int out_size, void* d_ws, size_t ws_size,
                              hipStream_t stream) {
    const float* x    = (const float*)d_in[0];
    const float4* phi = (const float4*)d_in[1];
    const float4* psi = (const float4*)d_in[2];
    unsigned short* mt = (unsigned short*)d_ws;    // 8*128*128 bf16 = 256KB
    float* out = (float*)d_out;

    const int rows    = in_sizes[0] / 1024;        // 65536
    const int ngroups = rows / 16;                 // 4096 (16-row groups/tile)
    const int blocks  = 8 * 128;                   // 128 blocks/tile; 4096/128=32 iters

    prep_kernel<<<8, 256, 0, stream>>>(phi, psi, mt);
    gemm_kernel<<<blocks, 256, 0, stream>>>(x, mt, out, ngroups);
}

// Round 13
// 131.460 us; speedup vs baseline: 1.5040x; 1.5040x over previous
//
#include <hip/hip_runtime.h>
#include <hip/hip_bf16.h>

// Resonance tiling via fused block-GEMM on MFMA — dedup streaming v4.
// Math: per tile t, [y1,y2] = [x1,x2] * M_t, M_t = [[I,Psi],[Phi,I+Phi*Psi]]
// (128x128 bf16, built once by prep_kernel into d_ws).
//
// Round-12 lesson: R11/R12 were saturating the memory request path but 1/3+
// of traffic was DUPLICATE x reads (waves sharing rows). This round each
// wave owns 16 exclusive rows and computes ALL 128 n-cols; M^T lives in
// LDS (32KB/block, staged once per persistent block) and a-fragments are
// re-read per iteration (LDS has 3x headroom vs the HBM round).
// Loop stays barrier-free; loads issued before stores (vmcnt ordering).

typedef __attribute__((ext_vector_type(8))) short bf16x8;
typedef __attribute__((ext_vector_type(4))) float f32x4;

static __device__ __forceinline__ unsigned short f2bf(float f) {
    unsigned u = __builtin_bit_cast(unsigned, f);
    unsigned r = 0x7FFFu + ((u >> 16) & 1u);     // round-to-nearest-even
    return (unsigned short)((u + r) >> 16);
}

static __device__ __forceinline__ short hwbf(float f) {
    __hip_bfloat16 h = __float2bfloat16(f);       // hardware v_cvt
    return __builtin_bit_cast(short, h);
}

// ---------------- pre-kernel: build M_t^T (bf16) ----------------
__global__ __launch_bounds__(256)
void prep_kernel(const float4* __restrict__ phi,
                 const float4* __restrict__ psi,
                 unsigned short* __restrict__ mt) {
    __shared__ float Phi[64][64];
    __shared__ float Psi[64][64];
    const int t   = blockIdx.x;          // 0..7
    const int tid = threadIdx.x;
    const int i   = tid >> 4, j = tid & 15;

    {   // Hamilton 4x4 block (row-vec convention, matches reference)
        float4 w = phi[t * 256 + i * 16 + j];
        float a = w.x, b = w.y, c = w.z, d = w.w;
        Phi[4*i+0][4*j+0]= a; Phi[4*i+0][4*j+1]= b; Phi[4*i+0][4*j+2]= c; Phi[4*i+0][4*j+3]= d;
        Phi[4*i+1][4*j+0]=-b; Phi[4*i+1][4*j+1]= a; Phi[4*i+1][4*j+2]=-d; Phi[4*i+1][4*j+3]= c;
        Phi[4*i+2][4*j+0]=-c; Phi[4*i+2][4*j+1]= d; Phi[4*i+2][4*j+2]= a; Phi[4*i+2][4*j+3]=-b;
        Phi[4*i+3][4*j+0]=-d; Phi[4*i+3][4*j+1]=-c; Phi[4*i+3][4*j+2]= b; Phi[4*i+3][4*j+3]= a;
        float4 v = psi[(8 + t) * 256 + i * 16 + j];
        a = v.x; b = v.y; c = v.z; d = v.w;
        Psi[4*i+0][4*j+0]= a; Psi[4*i+0][4*j+1]= b; Psi[4*i+0][4*j+2]= c; Psi[4*i+0][4*j+3]= d;
        Psi[4*i+1][4*j+0]=-b; Psi[4*i+1][4*j+1]= a; Psi[4*i+1][4*j+2]=-d; Psi[4*i+1][4*j+3]= c;
        Psi[4*i+2][4*j+0]=-c; Psi[4*i+2][4*j+1]= d; Psi[4*i+2][4*j+2]= a; Psi[4*i+2][4*j+3]=-b;
        Psi[4*i+3][4*j+0]=-d; Psi[4*i+3][4*j+1]=-c; Psi[4*i+3][4*j+2]= b; Psi[4*i+3][4*j+3]= a;
    }
    __syncthreads();

    unsigned short* m = mt + t * 16384;   // MT[n][k] = M[k][n]
    for (int e = tid; e < 16384; e += 256) {
        const int n = e >> 7, k = e & 127;
        if (n >= 64 && k >= 64) continue;
        float v;
        if (k < 64 && n < 64)       v = (k == n) ? 1.f : 0.f;   // M11 = I
        else if (k >= 64)           v = Phi[k - 64][n];          // M21 = Phi
        else                        v = Psi[k][n - 64];          // M12 = Psi
        m[e] = f2bf(v);
    }
    // M22 = I + Phi@Psi
    const int r = tid & 63, c0 = (tid >> 6) * 16;
    float pk[16];
#pragma unroll
    for (int cc = 0; cc < 16; ++cc) pk[cc] = 0.f;
    for (int k = 0; k < 64; ++k) {
        const float fr = Phi[r][k];
#pragma unroll
        for (int cc = 0; cc < 16; ++cc) pk[cc] = fmaf(fr, Psi[k][c0 + cc], pk[cc]);
    }
#pragma unroll
    for (int cc = 0; cc < 16; ++cc) {
        const int c = c0 + cc;
        m[(64 + c) * 128 + (64 + r)] = f2bf(((r == c) ? 1.f : 0.f) + pk[cc]);
    }
}

// ------------- main: dedup barrier-free streaming GEMM -------------
// wave = 16 EXCLUSIVE rows x all 128 n of tile t (operand-swapped MFMA:
// M^T a-frags from LDS, x as B-operand). block = 4 waves = 64 rows.
// Persistent blocks grid-stride; M^T staged to LDS once per block.
__global__ __launch_bounds__(256)
void gemm_kernel(const float* __restrict__ x,
                 const unsigned short* __restrict__ mt,
                 float* __restrict__ out,
                 int ngroups) {
    __shared__ __align__(16) short Ms[128 * 128];   // M^T[n][k] linear, 32KB

    const int tid  = threadIdx.x;
    const int lane = tid & 63;
    const int w    = tid >> 6;                  // wave 0..3 (16-row slice)
    const int ln = lane & 15, lk = lane >> 4;
    const int t  = blockIdx.x & 7;
    const int gs = gridDim.x >> 3;

    // stage this tile's M^T into LDS (once per persistent block)
    {
        const bf16x8* src = (const bf16x8*)(mt + t * 16384);
        bf16x8* dst = (bf16x8*)Ms;
#pragma unroll
        for (int i = 0; i < 8; ++i) dst[tid + i * 256] = src[tid + i * 256];
    }
    __syncthreads();

    const int ca = t * 64 + lk * 8;     // x f32 col base (+ks offsets)

    float4 L[8];
#define ISSUE(gg) { \
        const float* xr = x + ((size_t)(gg) * 64 + w * 16 + ln) * 1024 + ca; \
        L[0] = *(const float4*)(xr + 0);   L[1] = *(const float4*)(xr + 4); \
        L[2] = *(const float4*)(xr + 32);  L[3] = *(const float4*)(xr + 36); \
        L[4] = *(const float4*)(xr + 512); L[5] = *(const float4*)(xr + 516); \
        L[6] = *(const float4*)(xr + 544); L[7] = *(const float4*)(xr + 548); }

    int g = blockIdx.x >> 3;
    if (g < ngroups) ISSUE(g)

    while (g < ngroups) {
        // cvt L -> B-operand fragments (col = x-row = ln, 8 contiguous k)
        bf16x8 bx[4];
#pragma unroll
        for (int kk = 0; kk < 4; ++kk) {
            bx[kk][0] = hwbf(L[2*kk].x);   bx[kk][1] = hwbf(L[2*kk].y);
            bx[kk][2] = hwbf(L[2*kk].z);   bx[kk][3] = hwbf(L[2*kk].w);
            bx[kk][4] = hwbf(L[2*kk+1].x); bx[kk][5] = hwbf(L[2*kk+1].y);
            bx[kk][6] = hwbf(L[2*kk+1].z); bx[kk][7] = hwbf(L[2*kk+1].w);
        }

        // prefetch next group BEFORE stores (keeps stores out of the wait)
        const int gn = g + gs;
        if (gn < ngroups) ISSUE(gn)

        // MFMA: acc[fn] over all 8 n-fragments, K=128 in 4 steps
        f32x4 acc[8];
#pragma unroll
        for (int fn = 0; fn < 8; ++fn) acc[fn] = (f32x4)(0.f);
#pragma unroll
        for (int ks = 0; ks < 4; ++ks) {
#pragma unroll
            for (int fn = 0; fn < 8; ++fn) {
                const bf16x8 af = *(const bf16x8*)(Ms + (fn * 16 + ln) * 128
                                                      + ks * 32 + lk * 8);
                acc[fn] = __builtin_amdgcn_mfma_f32_16x16x32_bf16(
                    af, bx[ks], acc[fn], 0, 0, 0);
            }
        }

        // stores: lane = x-row ln; n = fn*16 + lk*4 + reg -> f32x4, full lines
        {
            float* orow = out + ((size_t)g * 64 + w * 16 + ln) * 1024;
#pragma unroll
            for (int fn = 0; fn < 8; ++fn) {
                const int col = ((fn < 4) ? t * 64 + fn * 16
                                          : 512 + t * 64 + (fn - 4) * 16) + lk * 4;
                *(f32x4*)(orow + col) = acc[fn];
            }
        }

        g = gn;
    }
#undef ISSUE
}

extern "C" void kernel_launch(void* const* d_in, const int* in_sizes, int n_in,
                              void* d_out, int out_size, void* d_ws, size_t ws_size,
                              hipStream_t stream) {
    const float* x    = (const float*)d_in[0];
    const float4* phi = (const float4*)d_in[1];
    const float4* psi = (const float4*)d_in[2];
    unsigned short* mt = (unsigned short*)d_ws;    // 8*128*128 bf16 = 256KB
    float* out = (float*)d_out;

    const int rows    = in_sizes[0] / 1024;        // 65536
    const int ngroups = rows / 64;                 // 1024 (64-row groups)
    const int blocks  = 8 * 128;                   // 4 blocks/CU; 8 iters each

    prep_kernel<<<8, 256, 0, stream>>>(phi, psi, mt);
    gemm_kernel<<<blocks, 256, 0, stream>>>(x, mt, out, ngroups);
}

// Round 14
// 118.007 us; speedup vs baseline: 1.6754x; 1.1140x over previous
//
#include <hip/hip_runtime.h>
#include <hip/hip_bf16.h>

// Resonance tiling via fused block-GEMM on MFMA — line-dense streaming v5.
// Math: per tile t, [y1,y2] = [x1,x2] * M_t, M_t = [[I,Psi],[Phi,I+Phi*Psi]]
// (128x128 bf16, built once by prep_kernel into d_ws).
//
// R13 lesson: HBM-level dedup was a non-problem (L3 retains x; FETCH was
// already ~132MB). Every kernel since R3 reads/writes 256B chunks at 4KB
// stride (per-tile columns) and all plateau ~4 TB/s while fillBuffer does
// 6.9 TB/s linear. This round: line-dense accesses.
//  - block = 16 rows x 4-tile group -> per row two 1KB-contiguous spans;
//    load thread-map gives 256B contiguous per instruction (4 full lines).
//  - x staged f32->bf16 in XOR-swizzled LDS (dbuf); M^T frags in registers
//    per (tile, n-half) wave; 16 MFMA/wave/chunk.
//  - outputs gathered in 32KB LDS, written back 256B-contiguous per instr.
//  - 1-chunk prefetch (loads issued before compute+stores), 2 barriers/chunk,
//    2 blocks/CU (launch_bounds(512,4) -> <=128 VGPR, 16 waves/CU).

typedef __attribute__((ext_vector_type(8))) short bf16x8;
typedef __attribute__((ext_vector_type(4))) float f32x4;

static __device__ __forceinline__ unsigned short f2bf(float f) {
    unsigned u = __builtin_bit_cast(unsigned, f);
    unsigned r = 0x7FFFu + ((u >> 16) & 1u);     // round-to-nearest-even
    return (unsigned short)((u + r) >> 16);
}

static __device__ __forceinline__ short hwbf(float f) {
    __hip_bfloat16 h = __float2bfloat16(f);       // hardware v_cvt
    return __builtin_bit_cast(short, h);
}

// ---------------- pre-kernel: build M_t^T (bf16) ----------------
__global__ __launch_bounds__(256)
void prep_kernel(const float4* __restrict__ phi,
                 const float4* __restrict__ psi,
                 unsigned short* __restrict__ mt) {
    __shared__ float Phi[64][64];
    __shared__ float Psi[64][64];
    const int t   = blockIdx.x;          // 0..7
    const int tid = threadIdx.x;
    const int i   = tid >> 4, j = tid & 15;

    {   // Hamilton 4x4 block (row-vec convention, matches reference)
        float4 w = phi[t * 256 + i * 16 + j];
        float a = w.x, b = w.y, c = w.z, d = w.w;
        Phi[4*i+0][4*j+0]= a; Phi[4*i+0][4*j+1]= b; Phi[4*i+0][4*j+2]= c; Phi[4*i+0][4*j+3]= d;
        Phi[4*i+1][4*j+0]=-b; Phi[4*i+1][4*j+1]= a; Phi[4*i+1][4*j+2]=-d; Phi[4*i+1][4*j+3]= c;
        Phi[4*i+2][4*j+0]=-c; Phi[4*i+2][4*j+1]= d; Phi[4*i+2][4*j+2]= a; Phi[4*i+2][4*j+3]=-b;
        Phi[4*i+3][4*j+0]=-d; Phi[4*i+3][4*j+1]=-c; Phi[4*i+3][4*j+2]= b; Phi[4*i+3][4*j+3]= a;
        float4 v = psi[(8 + t) * 256 + i * 16 + j];
        a = v.x; b = v.y; c = v.z; d = v.w;
        Psi[4*i+0][4*j+0]= a; Psi[4*i+0][4*j+1]= b; Psi[4*i+0][4*j+2]= c; Psi[4*i+0][4*j+3]= d;
        Psi[4*i+1][4*j+0]=-b; Psi[4*i+1][4*j+1]= a; Psi[4*i+1][4*j+2]=-d; Psi[4*i+1][4*j+3]= c;
        Psi[4*i+2][4*j+0]=-c; Psi[4*i+2][4*j+1]= d; Psi[4*i+2][4*j+2]= a; Psi[4*i+2][4*j+3]=-b;
        Psi[4*i+3][4*j+0]=-d; Psi[4*i+3][4*j+1]=-c; Psi[4*i+3][4*j+2]= b; Psi[4*i+3][4*j+3]= a;
    }
    __syncthreads();

    unsigned short* m = mt + t * 16384;   // MT[n][k] = M[k][n]
    for (int e = tid; e < 16384; e += 256) {
        const int n = e >> 7, k = e & 127;
        if (n >= 64 && k >= 64) continue;
        float v;
        if (k < 64 && n < 64)       v = (k == n) ? 1.f : 0.f;   // M11 = I
        else if (k >= 64)           v = Phi[k - 64][n];          // M21 = Phi
        else                        v = Psi[k][n - 64];          // M12 = Psi
        m[e] = f2bf(v);
    }
    // M22 = I + Phi@Psi
    const int r = tid & 63, c0 = (tid >> 6) * 16;
    float pk[16];
#pragma unroll
    for (int cc = 0; cc < 16; ++cc) pk[cc] = 0.f;
    for (int k = 0; k < 64; ++k) {
        const float fr = Phi[r][k];
#pragma unroll
        for (int cc = 0; cc < 16; ++cc) pk[cc] = fmaf(fr, Psi[k][c0 + cc], pk[cc]);
    }
#pragma unroll
    for (int cc = 0; cc < 16; ++cc) {
        const int c = c0 + cc;
        m[(64 + c) * 128 + (64 + r)] = f2bf(((r == c) ? 1.f : 0.f) + pk[cc]);
    }
}

// ------------- main: line-dense LDS-staged streaming GEMM -------------
__global__ __launch_bounds__(512, 4)
void gemm_kernel(const float* __restrict__ x,
                 const unsigned short* __restrict__ mt,
                 float* __restrict__ out,
                 int nchunks) {
    __shared__ __align__(16) char inbuf[2][16384];   // 16 rows x 512 bf16, swz
    __shared__ __align__(16) char outbuf[32768];     // 16 rows x 512 f32, swz

    const int tid  = threadIdx.x;
    const int tg   = blockIdx.x & 1;        // tile group: tiles tg*4..tg*4+3
    const int bc   = blockIdx.x >> 1;       // 0..255
    const int cs   = gridDim.x >> 1;        // chunk stride (256)
    const int lane = tid & 63, w = tid >> 6;
    const int twl  = w >> 1, hw = w & 1;    // tile-in-group, n-half
    const int twg  = tg * 4 + twl;
    const int ln = lane & 15, lk = lane >> 4;

    // M^T fragments for (tile twg, n-half hw): 64 VGPR, persistent
    bf16x8 a[4][4];
    {
        const unsigned short* mtt = mt + twg * 16384;
#pragma unroll
        for (int fn = 0; fn < 4; ++fn)
#pragma unroll
            for (int ks = 0; ks < 4; ++ks)
                a[fn][ks] = *(const bf16x8*)(mtt + (hw*64 + fn*16 + ln)*128
                                                 + ks*32 + lk*8);
    }

    // staging map: thread = (row sr, span shalf, seg sseg)
    const int sr    = tid >> 5;        // 0..15
    const int sp    = tid & 31;
    const int shalf = sp >> 4;         // 0: x1-span, 1: x2-span
    const int sseg  = sp & 15;
    const size_t gcb = (size_t)(shalf ? 512 : 0) + tg * 256 + sseg * 4;
    const int swz   = (sr & 7) << 4;

    float4 L[4];
#define ISSUE(cc) { \
        const float* xr = x + ((size_t)(cc) * 16 + sr) * 1024 + gcb; \
        L[0] = *(const float4*)(xr);        L[1] = *(const float4*)(xr + 64); \
        L[2] = *(const float4*)(xr + 128);  L[3] = *(const float4*)(xr + 192); }

    int c = bc;
    if (c < nchunks) ISSUE(c)

    int cur = 0;
    while (c < nchunks) {
        // ---- 1: pack L (chunk c) -> inbuf[cur], 4x 8B swizzled writes ----
#pragma unroll
        for (int l = 0; l < 4; ++l) {
            short4 h;
            h.x = hwbf(L[l].x); h.y = hwbf(L[l].y);
            h.z = hwbf(L[l].z); h.w = hwbf(L[l].w);
            const int byte = (sr * 1024 + (shalf * 256 + sseg * 4 + l * 64) * 2) ^ swz;
            *(short4*)(inbuf[cur] + byte) = h;
        }
        __syncthreads();

        // ---- 2: issue next chunk's loads (before compute & stores) ----
        const int cn = c + cs;
        if (cn < nchunks) ISSUE(cn)

        // ---- 3: compute: B-frags from inbuf, 16 MFMA ----
        f32x4 acc[4];
#pragma unroll
        for (int fn = 0; fn < 4; ++fn) acc[fn] = (f32x4)(0.f);
#pragma unroll
        for (int ks = 0; ks < 4; ++ks) {
            const int lcol = (ks < 2) ? (twl * 64 + ks * 32 + lk * 8)
                                      : (256 + twl * 64 + (ks - 2) * 32 + lk * 8);
            const int byte = (ln * 1024 + lcol * 2) ^ ((ln & 7) << 4);
            const bf16x8 bx = *(const bf16x8*)(inbuf[cur] + byte);
#pragma unroll
            for (int fn = 0; fn < 4; ++fn)
                acc[fn] = __builtin_amdgcn_mfma_f32_16x16x32_bf16(
                    a[fn][ks], bx, acc[fn], 0, 0, 0);
        }

        // ---- 4: acc -> outbuf (swizzled f32x4) ----
#pragma unroll
        for (int fn = 0; fn < 4; ++fn) {
            const int lcolf = hw * 256 + twl * 64 + fn * 16 + lk * 4;
            const int byte  = (ln * 2048 + lcolf * 4) ^ ((ln & 7) << 4);
            *(f32x4*)(outbuf + byte) = acc[fn];
        }
        __syncthreads();

        // ---- 5: outbuf -> global, 256B-contiguous per instruction ----
        {
            float* orow = out + ((size_t)c * 16 + sr) * 1024 + gcb;
#pragma unroll
            for (int l = 0; l < 4; ++l) {
                const int byte = (sr * 2048 + (shalf * 256 + sseg * 4 + l * 64) * 4) ^ swz;
                *(f32x4*)(orow + l * 64) = *(const f32x4*)(outbuf + byte);
            }
        }

        cur ^= 1;
        c = cn;
    }
#undef ISSUE
}

extern "C" void kernel_launch(void* const* d_in, const int* in_sizes, int n_in,
                              void* d_out, int out_size, void* d_ws, size_t ws_size,
                              hipStream_t stream) {
    const float* x    = (const float*)d_in[0];
    const float4* phi = (const float4*)d_in[1];
    const float4* psi = (const float4*)d_in[2];
    unsigned short* mt = (unsigned short*)d_ws;    // 8*128*128 bf16 = 256KB
    float* out = (float*)d_out;

    const int rows    = in_sizes[0] / 1024;        // 65536
    const int nchunks = rows / 16;                 // 4096
    const int blocks  = 512;                       // 2 tile-groups x 256

    prep_kernel<<<8, 256, 0, stream>>>(phi, psi, mt);
    gemm_kernel<<<blocks, 512, 0, stream>>>(x, mt, out, nchunks);
}

// Round 15
// 117.090 us; speedup vs baseline: 1.6885x; 1.0078x over previous
//
#include <hip/hip_runtime.h>
#include <hip/hip_bf16.h>

// Resonance tiling via fused block-GEMM on MFMA — single-barrier v6.
// Math: per tile t, [y1,y2] = [x1,x2] * M_t, M_t = [[I,Psi],[Phi,I+Phi*Psi]]
// (128x128 bf16, built once by prep_kernel into d_ws).
//
// R14 lessons: line-dense reads helped (124.7->118) but two barriers/chunk
// (each draining vmcnt to 0: prefetch loads at one, stores at the other)
// with only 2 blocks/CU left ~30us of stall. Writes never needed LDS
// gather (WRITE=262MB exact with scattered f32x4 in R8/9/11 — L2 combines).
// This round: 256-thr block = 16 rows x tile-PAIR, LDS 16KB (inbuf dbuf
// only) -> 4 blocks/CU; ONE barrier per chunk; direct acc stores; loads
// issued right after barrier (prefetch c+1 never drained by anything).

typedef __attribute__((ext_vector_type(8))) short bf16x8;
typedef __attribute__((ext_vector_type(4))) float f32x4;

static __device__ __forceinline__ unsigned short f2bf(float f) {
    unsigned u = __builtin_bit_cast(unsigned, f);
    unsigned r = 0x7FFFu + ((u >> 16) & 1u);     // round-to-nearest-even
    return (unsigned short)((u + r) >> 16);
}

static __device__ __forceinline__ short hwbf(float f) {
    __hip_bfloat16 h = __float2bfloat16(f);       // hardware v_cvt
    return __builtin_bit_cast(short, h);
}

// ---------------- pre-kernel: build M_t^T (bf16) ----------------
__global__ __launch_bounds__(256)
void prep_kernel(const float4* __restrict__ phi,
                 const float4* __restrict__ psi,
                 unsigned short* __restrict__ mt) {
    __shared__ float Phi[64][64];
    __shared__ float Psi[64][64];
    const int t   = blockIdx.x;          // 0..7
    const int tid = threadIdx.x;
    const int i   = tid >> 4, j = tid & 15;

    {   // Hamilton 4x4 block (row-vec convention, matches reference)
        float4 w = phi[t * 256 + i * 16 + j];
        float a = w.x, b = w.y, c = w.z, d = w.w;
        Phi[4*i+0][4*j+0]= a; Phi[4*i+0][4*j+1]= b; Phi[4*i+0][4*j+2]= c; Phi[4*i+0][4*j+3]= d;
        Phi[4*i+1][4*j+0]=-b; Phi[4*i+1][4*j+1]= a; Phi[4*i+1][4*j+2]=-d; Phi[4*i+1][4*j+3]= c;
        Phi[4*i+2][4*j+0]=-c; Phi[4*i+2][4*j+1]= d; Phi[4*i+2][4*j+2]= a; Phi[4*i+2][4*j+3]=-b;
        Phi[4*i+3][4*j+0]=-d; Phi[4*i+3][4*j+1]=-c; Phi[4*i+3][4*j+2]= b; Phi[4*i+3][4*j+3]= a;
        float4 v = psi[(8 + t) * 256 + i * 16 + j];
        a = v.x; b = v.y; c = v.z; d = v.w;
        Psi[4*i+0][4*j+0]= a; Psi[4*i+0][4*j+1]= b; Psi[4*i+0][4*j+2]= c; Psi[4*i+0][4*j+3]= d;
        Psi[4*i+1][4*j+0]=-b; Psi[4*i+1][4*j+1]= a; Psi[4*i+1][4*j+2]=-d; Psi[4*i+1][4*j+3]= c;
        Psi[4*i+2][4*j+0]=-c; Psi[4*i+2][4*j+1]= d; Psi[4*i+2][4*j+2]= a; Psi[4*i+2][4*j+3]=-b;
        Psi[4*i+3][4*j+0]=-d; Psi[4*i+3][4*j+1]=-c; Psi[4*i+3][4*j+2]= b; Psi[4*i+3][4*j+3]= a;
    }
    __syncthreads();

    unsigned short* m = mt + t * 16384;   // MT[n][k] = M[k][n]
    for (int e = tid; e < 16384; e += 256) {
        const int n = e >> 7, k = e & 127;
        if (n >= 64 && k >= 64) continue;
        float v;
        if (k < 64 && n < 64)       v = (k == n) ? 1.f : 0.f;   // M11 = I
        else if (k >= 64)           v = Phi[k - 64][n];          // M21 = Phi
        else                        v = Psi[k][n - 64];          // M12 = Psi
        m[e] = f2bf(v);
    }
    // M22 = I + Phi@Psi
    const int r = tid & 63, c0 = (tid >> 6) * 16;
    float pk[16];
#pragma unroll
    for (int cc = 0; cc < 16; ++cc) pk[cc] = 0.f;
    for (int k = 0; k < 64; ++k) {
        const float fr = Phi[r][k];
#pragma unroll
        for (int cc = 0; cc < 16; ++cc) pk[cc] = fmaf(fr, Psi[k][c0 + cc], pk[cc]);
    }
#pragma unroll
    for (int cc = 0; cc < 16; ++cc) {
        const int c = c0 + cc;
        m[(64 + c) * 128 + (64 + r)] = f2bf(((r == c) ? 1.f : 0.f) + pk[cc]);
    }
}

// ------- main: single-barrier, line-dense-read streaming GEMM -------
// block = 16 rows x tile-pair pr (tiles 2pr, 2pr+1). 4 waves: (tw, hw).
// inbuf: [16 rows][256 bf16] XOR-swizzled, double-buffered (16KB total).
__global__ __launch_bounds__(256, 4)
void gemm_kernel(const float* __restrict__ x,
                 const unsigned short* __restrict__ mt,
                 float* __restrict__ out,
                 int nchunks) {
    __shared__ __align__(16) char inbuf[2][8192];

    const int tid  = threadIdx.x;
    const int pr   = blockIdx.x & 3;        // tile pair 0..3
    const int bc   = blockIdx.x >> 2;       // 0..255
    const int cs   = gridDim.x >> 2;        // chunk stride
    const int lane = tid & 63, w = tid >> 6;
    const int tw = w >> 1, hw = w & 1;      // tile-in-pair, n-half
    const int twg = pr * 2 + tw;
    const int ln = lane & 15, lk = lane >> 4;

    // M^T fragments for (tile twg, n-half hw): 64 VGPR, persistent
    bf16x8 a[4][4];
    {
        const unsigned short* mtt = mt + twg * 16384;
#pragma unroll
        for (int fn = 0; fn < 4; ++fn)
#pragma unroll
            for (int ks = 0; ks < 4; ++ks)
                a[fn][ks] = *(const bf16x8*)(mtt + (hw*64 + fn*16 + ln)*128
                                                 + ks*32 + lk*8);
    }

    // staging map: thread = (row sr, seg 0..15); 32B per span per thread
    const int sr  = tid >> 4, seg = tid & 15;
    const size_t gb  = (size_t)pr * 128 + seg * 8;   // f32 col of x1 span
    const int    swz = (sr & 7) << 4;

    float4 L[4];
#define ISSUE(cc) { \
        const float* xr = x + ((size_t)(cc) * 16 + sr) * 1024 + gb; \
        L[0] = *(const float4*)(xr);       L[1] = *(const float4*)(xr + 4); \
        L[2] = *(const float4*)(xr + 512); L[3] = *(const float4*)(xr + 516); }

    int c = bc;
    if (c < nchunks) ISSUE(c)

    int cur = 0;
    while (c < nchunks) {
        // ---- pack chunk c -> inbuf[cur] (waits only on loads(c)) ----
        {
            bf16x8 h0, h1;
            h0[0] = hwbf(L[0].x); h0[1] = hwbf(L[0].y);
            h0[2] = hwbf(L[0].z); h0[3] = hwbf(L[0].w);
            h0[4] = hwbf(L[1].x); h0[5] = hwbf(L[1].y);
            h0[6] = hwbf(L[1].z); h0[7] = hwbf(L[1].w);
            h1[0] = hwbf(L[2].x); h1[1] = hwbf(L[2].y);
            h1[2] = hwbf(L[2].z); h1[3] = hwbf(L[2].w);
            h1[4] = hwbf(L[3].x); h1[5] = hwbf(L[3].y);
            h1[6] = hwbf(L[3].z); h1[7] = hwbf(L[3].w);
            *(bf16x8*)(inbuf[cur] + ((sr * 512 + seg * 16) ^ swz))       = h0;
            *(bf16x8*)(inbuf[cur] + ((sr * 512 + 256 + seg * 16) ^ swz)) = h1;
        }
        __syncthreads();        // single barrier per chunk

        // ---- prefetch next chunk (nothing ever drains these) ----
        const int cn = c + cs;
        if (cn < nchunks) ISSUE(cn)

        // ---- compute from inbuf[cur]: 16 MFMA ----
        f32x4 acc[4];
#pragma unroll
        for (int fn = 0; fn < 4; ++fn) acc[fn] = (f32x4)(0.f);
#pragma unroll
        for (int ks = 0; ks < 4; ++ks) {
            const int col = ((ks < 2) ? tw * 64 + ks * 32
                                      : 128 + tw * 64 + (ks - 2) * 32) + lk * 8;
            const bf16x8 bx = *(const bf16x8*)(inbuf[cur]
                                + ((ln * 512 + col * 2) ^ ((ln & 7) << 4)));
#pragma unroll
            for (int fn = 0; fn < 4; ++fn)
                acc[fn] = __builtin_amdgcn_mfma_f32_16x16x32_bf16(
                    a[fn][ks], bx, acc[fn], 0, 0, 0);
        }

        // ---- direct stores from acc (L2 write-combines; proven clean) ----
        {
            float* orow = out + ((size_t)c * 16 + ln) * 1024;
#pragma unroll
            for (int fn = 0; fn < 4; ++fn) {
                const int colo = ((hw == 0) ? twg * 64 + fn * 16
                                            : 512 + twg * 64 + fn * 16) + lk * 4;
                *(f32x4*)(orow + colo) = acc[fn];
            }
        }

        cur ^= 1;
        c = cn;
    }
#undef ISSUE
}

extern "C" void kernel_launch(void* const* d_in, const int* in_sizes, int n_in,
                              void* d_out, int out_size, void* d_ws, size_t ws_size,
                              hipStream_t stream) {
    const float* x    = (const float*)d_in[0];
    const float4* phi = (const float4*)d_in[1];
    const float4* psi = (const float4*)d_in[2];
    unsigned short* mt = (unsigned short*)d_ws;    // 8*128*128 bf16 = 256KB
    float* out = (float*)d_out;

    const int rows    = in_sizes[0] / 1024;        // 65536
    const int nchunks = rows / 16;                 // 4096
    const int blocks  = 4 * 256;                   // 4 tile-pairs x 256

    prep_kernel<<<8, 256, 0, stream>>>(phi, psi, mt);
    gemm_kernel<<<blocks, 256, 0, stream>>>(x, mt, out, nchunks);
}

// Round 16
// 102.910 us; speedup vs baseline: 1.9212x; 1.1378x over previous
//
#include <hip/hip_runtime.h>
#include <hip/hip_bf16.h>

// Resonance tiling via fused block-GEMM on MFMA — nt-write v7.
// Math: per tile t, [y1,y2] = [x1,x2] * M_t, M_t = [[I,Psi],[Phi,I+Phi*Psi]]
// (128x128 bf16, built once by prep_kernel into d_ws).
//
// R15 lesson: barrier/occupancy variations null; all structures pin at
// ~4.6 TB/s. Hypothesis: 256MB/replay of output ALLOCATES in L3 and evicts
// x (FETCH ~140MB = half of x re-fetched). This round:
//  - gather acc into 16KB out-LDS, write back 256B-contiguous per
//    instruction (full lines), with __builtin_nontemporal_store -> stream
//    writes past L3, keep x resident (R11's nt failed on PARTIAL lines).
//  - raw barriers: s_waitcnt lgkmcnt(0) + s_barrier (no vmcnt drain ever;
//    prefetch loads and nt stores stay in flight across iterations).
//  - rest = v6: 256thr, tile-pair/block, inbuf dbuf 16KB, load-before-store.

typedef __attribute__((ext_vector_type(8))) short bf16x8;
typedef __attribute__((ext_vector_type(4))) float f32x4;

static __device__ __forceinline__ unsigned short f2bf(float f) {
    unsigned u = __builtin_bit_cast(unsigned, f);
    unsigned r = 0x7FFFu + ((u >> 16) & 1u);     // round-to-nearest-even
    return (unsigned short)((u + r) >> 16);
}

static __device__ __forceinline__ short hwbf(float f) {
    __hip_bfloat16 h = __float2bfloat16(f);       // hardware v_cvt
    return __builtin_bit_cast(short, h);
}

// ---------------- pre-kernel: build M_t^T (bf16) ----------------
__global__ __launch_bounds__(256)
void prep_kernel(const float4* __restrict__ phi,
                 const float4* __restrict__ psi,
                 unsigned short* __restrict__ mt) {
    __shared__ float Phi[64][64];
    __shared__ float Psi[64][64];
    const int t   = blockIdx.x;          // 0..7
    const int tid = threadIdx.x;
    const int i   = tid >> 4, j = tid & 15;

    {   // Hamilton 4x4 block (row-vec convention, matches reference)
        float4 w = phi[t * 256 + i * 16 + j];
        float a = w.x, b = w.y, c = w.z, d = w.w;
        Phi[4*i+0][4*j+0]= a; Phi[4*i+0][4*j+1]= b; Phi[4*i+0][4*j+2]= c; Phi[4*i+0][4*j+3]= d;
        Phi[4*i+1][4*j+0]=-b; Phi[4*i+1][4*j+1]= a; Phi[4*i+1][4*j+2]=-d; Phi[4*i+1][4*j+3]= c;
        Phi[4*i+2][4*j+0]=-c; Phi[4*i+2][4*j+1]= d; Phi[4*i+2][4*j+2]= a; Phi[4*i+2][4*j+3]=-b;
        Phi[4*i+3][4*j+0]=-d; Phi[4*i+3][4*j+1]=-c; Phi[4*i+3][4*j+2]= b; Phi[4*i+3][4*j+3]= a;
        float4 v = psi[(8 + t) * 256 + i * 16 + j];
        a = v.x; b = v.y; c = v.z; d = v.w;
        Psi[4*i+0][4*j+0]= a; Psi[4*i+0][4*j+1]= b; Psi[4*i+0][4*j+2]= c; Psi[4*i+0][4*j+3]= d;
        Psi[4*i+1][4*j+0]=-b; Psi[4*i+1][4*j+1]= a; Psi[4*i+1][4*j+2]=-d; Psi[4*i+1][4*j+3]= c;
        Psi[4*i+2][4*j+0]=-c; Psi[4*i+2][4*j+1]= d; Psi[4*i+2][4*j+2]= a; Psi[4*i+2][4*j+3]=-b;
        Psi[4*i+3][4*j+0]=-d; Psi[4*i+3][4*j+1]=-c; Psi[4*i+3][4*j+2]= b; Psi[4*i+3][4*j+3]= a;
    }
    __syncthreads();

    unsigned short* m = mt + t * 16384;   // MT[n][k] = M[k][n]
    for (int e = tid; e < 16384; e += 256) {
        const int n = e >> 7, k = e & 127;
        if (n >= 64 && k >= 64) continue;
        float v;
        if (k < 64 && n < 64)       v = (k == n) ? 1.f : 0.f;   // M11 = I
        else if (k >= 64)           v = Phi[k - 64][n];          // M21 = Phi
        else                        v = Psi[k][n - 64];          // M12 = Psi
        m[e] = f2bf(v);
    }
    // M22 = I + Phi@Psi
    const int r = tid & 63, c0 = (tid >> 6) * 16;
    float pk[16];
#pragma unroll
    for (int cc = 0; cc < 16; ++cc) pk[cc] = 0.f;
    for (int k = 0; k < 64; ++k) {
        const float fr = Phi[r][k];
#pragma unroll
        for (int cc = 0; cc < 16; ++cc) pk[cc] = fmaf(fr, Psi[k][c0 + cc], pk[cc]);
    }
#pragma unroll
    for (int cc = 0; cc < 16; ++cc) {
        const int c = c0 + cc;
        m[(64 + c) * 128 + (64 + r)] = f2bf(((r == c) ? 1.f : 0.f) + pk[cc]);
    }
}

// ------- main: nt full-line writes, raw barriers, line-dense reads -------
// block = 16 rows x tile-pair pr. 4 waves (tw, hw). inbuf 2x8KB swizzled;
// outbuf 16KB [16 rows][256 f32] linear (LDS conflicts off critical path).
__global__ __launch_bounds__(256, 4)
void gemm_kernel(const float* __restrict__ x,
                 const unsigned short* __restrict__ mt,
                 float* __restrict__ out,
                 int nchunks) {
    __shared__ __align__(16) char  inbuf[2][8192];
    __shared__ __align__(16) float outbuf[16 * 256];

    const int tid  = threadIdx.x;
    const int pr   = blockIdx.x & 3;        // tile pair 0..3
    const int bc   = blockIdx.x >> 2;       // 0..255
    const int cs   = gridDim.x >> 2;        // chunk stride
    const int lane = tid & 63, w = tid >> 6;
    const int tw = w >> 1, hw = w & 1;      // tile-in-pair, n-half
    const int twg = pr * 2 + tw;
    const int ln = lane & 15, lk = lane >> 4;

    // M^T fragments for (tile twg, n-half hw): 64 VGPR, persistent
    bf16x8 a[4][4];
    {
        const unsigned short* mtt = mt + twg * 16384;
#pragma unroll
        for (int fn = 0; fn < 4; ++fn)
#pragma unroll
            for (int ks = 0; ks < 4; ++ks)
                a[fn][ks] = *(const bf16x8*)(mtt + (hw*64 + fn*16 + ln)*128
                                                 + ks*32 + lk*8);
    }

    // staging map: thread = (row sr, seg 0..15); 32B per span per thread
    const int sr  = tid >> 4, seg = tid & 15;
    const size_t gb  = (size_t)pr * 128 + seg * 8;   // f32 col of x1 span
    const int    swz = (sr & 7) << 4;

    float4 L[4];
#define ISSUE(cc) { \
        const float* xr = x + ((size_t)(cc) * 16 + sr) * 1024 + gb; \
        L[0] = *(const float4*)(xr);       L[1] = *(const float4*)(xr + 4); \
        L[2] = *(const float4*)(xr + 512); L[3] = *(const float4*)(xr + 516); }

    int c = bc;
    if (c < nchunks) ISSUE(c)

    int cur = 0;
    while (c < nchunks) {
        // ---- pack chunk c -> inbuf[cur] (compiler waits only on L(c)) ----
        {
            bf16x8 h0, h1;
            h0[0] = hwbf(L[0].x); h0[1] = hwbf(L[0].y);
            h0[2] = hwbf(L[0].z); h0[3] = hwbf(L[0].w);
            h0[4] = hwbf(L[1].x); h0[5] = hwbf(L[1].y);
            h0[6] = hwbf(L[1].z); h0[7] = hwbf(L[1].w);
            h1[0] = hwbf(L[2].x); h1[1] = hwbf(L[2].y);
            h1[2] = hwbf(L[2].z); h1[3] = hwbf(L[2].w);
            h1[4] = hwbf(L[3].x); h1[5] = hwbf(L[3].y);
            h1[6] = hwbf(L[3].z); h1[7] = hwbf(L[3].w);
            *(bf16x8*)(inbuf[cur] + ((sr * 512 + seg * 16) ^ swz))       = h0;
            *(bf16x8*)(inbuf[cur] + ((sr * 512 + 256 + seg * 16) ^ swz)) = h1;
        }
        // barrier A: LDS visibility only — no vmcnt drain
        asm volatile("s_waitcnt lgkmcnt(0)" ::: "memory");
        __builtin_amdgcn_s_barrier();
        __builtin_amdgcn_sched_barrier(0);

        // ---- prefetch next chunk (never drained by anything) ----
        const int cn = c + cs;
        if (cn < nchunks) ISSUE(cn)

        // ---- compute from inbuf[cur]: 16 MFMA ----
        f32x4 acc[4];
#pragma unroll
        for (int fn = 0; fn < 4; ++fn) acc[fn] = (f32x4)(0.f);
#pragma unroll
        for (int ks = 0; ks < 4; ++ks) {
            const int col = ((ks < 2) ? tw * 64 + ks * 32
                                      : 128 + tw * 64 + (ks - 2) * 32) + lk * 8;
            const bf16x8 bx = *(const bf16x8*)(inbuf[cur]
                                + ((ln * 512 + col * 2) ^ ((ln & 7) << 4)));
#pragma unroll
            for (int fn = 0; fn < 4; ++fn)
                acc[fn] = __builtin_amdgcn_mfma_f32_16x16x32_bf16(
                    a[fn][ks], bx, acc[fn], 0, 0, 0);
        }

        // ---- acc -> outbuf (chunk-local col m = tw*64+fn*16+lk*4+hw*128) ----
#pragma unroll
        for (int fn = 0; fn < 4; ++fn) {
            const int m = tw * 64 + fn * 16 + lk * 4 + hw * 128;
            *(f32x4*)(outbuf + ln * 256 + m) = acc[fn];
        }
        // barrier B: LDS visibility only
        asm volatile("s_waitcnt lgkmcnt(0)" ::: "memory");
        __builtin_amdgcn_s_barrier();
        __builtin_amdgcn_sched_barrier(0);

        // ---- writeback: 256B-contiguous nt per instruction (full lines) ----
        {
            float* orow = out + ((size_t)c * 16 + sr) * 1024;
#pragma unroll
            for (int l = 0; l < 4; ++l) {
                const int m2 = seg * 4 + l * 64;     // chunk-local f32 col
                const int gcol = (m2 < 128) ? (int)(pr * 128 + m2)
                                            : (int)(512 + pr * 128 + (m2 - 128));
                const f32x4 v = *(const f32x4*)(outbuf + sr * 256 + m2);
                __builtin_nontemporal_store(v, (f32x4*)(orow + gcol));
            }
        }

        cur ^= 1;
        c = cn;
    }
#undef ISSUE
}

extern "C" void kernel_launch(void* const* d_in, const int* in_sizes, int n_in,
                              void* d_out, int out_size, void* d_ws, size_t ws_size,
                              hipStream_t stream) {
    const float* x    = (const float*)d_in[0];
    const float4* phi = (const float4*)d_in[1];
    const float4* psi = (const float4*)d_in[2];
    unsigned short* mt = (unsigned short*)d_ws;    // 8*128*128 bf16 = 256KB
    float* out = (float*)d_out;

    const int rows    = in_sizes[0] / 1024;        // 65536
    const int nchunks = rows / 16;                 // 4096
    const int blocks  = 4 * 256;                   // 4 tile-pairs x 256

    prep_kernel<<<8, 256, 0, stream>>>(phi, psi, mt);
    gemm_kernel<<<blocks, 256, 0, stream>>>(x, mt, out, nchunks);
}

// Round 17
// 102.257 us; speedup vs baseline: 1.9335x; 1.0064x over previous
//
#include <hip/hip_runtime.h>
#include <hip/hip_bf16.h>

// Resonance tiling via fused block-GEMM on MFMA — dense-read v8.
// Math: per tile t, [y1,y2] = [x1,x2] * M_t, M_t = [[I,Psi],[Phi,I+Phi*Psi]]
// (128x128 bf16, built once by prep_kernel into d_ws).
//
// R16 confirmed: nt full-line writes keep x L3-resident (117->103us).
// Remaining inefficiency: read map was HALF-DENSE per instruction (16B
// loaded every 32B within a lane-group). This round: interleaved read map
// — L[0] at +seg*4, L[1] at +64+seg*4 etc. -> every load instruction is
// 256B contiguous per 16-lane row-group (full lines, full density).
// Pack becomes 4x 8B LDS writes at k = {0,64,128,192}+seg*4. Everything
// else identical to v7 (raw lgkm-only barriers, nt writeback via out-LDS).

typedef __attribute__((ext_vector_type(8))) short bf16x8;
typedef __attribute__((ext_vector_type(4))) float f32x4;

static __device__ __forceinline__ unsigned short f2bf(float f) {
    unsigned u = __builtin_bit_cast(unsigned, f);
    unsigned r = 0x7FFFu + ((u >> 16) & 1u);     // round-to-nearest-even
    return (unsigned short)((u + r) >> 16);
}

static __device__ __forceinline__ short hwbf(float f) {
    __hip_bfloat16 h = __float2bfloat16(f);       // hardware v_cvt
    return __builtin_bit_cast(short, h);
}

// ---------------- pre-kernel: build M_t^T (bf16) ----------------
__global__ __launch_bounds__(256)
void prep_kernel(const float4* __restrict__ phi,
                 const float4* __restrict__ psi,
                 unsigned short* __restrict__ mt) {
    __shared__ float Phi[64][64];
    __shared__ float Psi[64][64];
    const int t   = blockIdx.x;          // 0..7
    const int tid = threadIdx.x;
    const int i   = tid >> 4, j = tid & 15;

    {   // Hamilton 4x4 block (row-vec convention, matches reference)
        float4 w = phi[t * 256 + i * 16 + j];
        float a = w.x, b = w.y, c = w.z, d = w.w;
        Phi[4*i+0][4*j+0]= a; Phi[4*i+0][4*j+1]= b; Phi[4*i+0][4*j+2]= c; Phi[4*i+0][4*j+3]= d;
        Phi[4*i+1][4*j+0]=-b; Phi[4*i+1][4*j+1]= a; Phi[4*i+1][4*j+2]=-d; Phi[4*i+1][4*j+3]= c;
        Phi[4*i+2][4*j+0]=-c; Phi[4*i+2][4*j+1]= d; Phi[4*i+2][4*j+2]= a; Phi[4*i+2][4*j+3]=-b;
        Phi[4*i+3][4*j+0]=-d; Phi[4*i+3][4*j+1]=-c; Phi[4*i+3][4*j+2]= b; Phi[4*i+3][4*j+3]= a;
        float4 v = psi[(8 + t) * 256 + i * 16 + j];
        a = v.x; b = v.y; c = v.z; d = v.w;
        Psi[4*i+0][4*j+0]= a; Psi[4*i+0][4*j+1]= b; Psi[4*i+0][4*j+2]= c; Psi[4*i+0][4*j+3]= d;
        Psi[4*i+1][4*j+0]=-b; Psi[4*i+1][4*j+1]= a; Psi[4*i+1][4*j+2]=-d; Psi[4*i+1][4*j+3]= c;
        Psi[4*i+2][4*j+0]=-c; Psi[4*i+2][4*j+1]= d; Psi[4*i+2][4*j+2]= a; Psi[4*i+2][4*j+3]=-b;
        Psi[4*i+3][4*j+0]=-d; Psi[4*i+3][4*j+1]=-c; Psi[4*i+3][4*j+2]= b; Psi[4*i+3][4*j+3]= a;
    }
    __syncthreads();

    unsigned short* m = mt + t * 16384;   // MT[n][k] = M[k][n]
    for (int e = tid; e < 16384; e += 256) {
        const int n = e >> 7, k = e & 127;
        if (n >= 64 && k >= 64) continue;
        float v;
        if (k < 64 && n < 64)       v = (k == n) ? 1.f : 0.f;   // M11 = I
        else if (k >= 64)           v = Phi[k - 64][n];          // M21 = Phi
        else                        v = Psi[k][n - 64];          // M12 = Psi
        m[e] = f2bf(v);
    }
    // M22 = I + Phi@Psi
    const int r = tid & 63, c0 = (tid >> 6) * 16;
    float pk[16];
#pragma unroll
    for (int cc = 0; cc < 16; ++cc) pk[cc] = 0.f;
    for (int k = 0; k < 64; ++k) {
        const float fr = Phi[r][k];
#pragma unroll
        for (int cc = 0; cc < 16; ++cc) pk[cc] = fmaf(fr, Psi[k][c0 + cc], pk[cc]);
    }
#pragma unroll
    for (int cc = 0; cc < 16; ++cc) {
        const int c = c0 + cc;
        m[(64 + c) * 128 + (64 + r)] = f2bf(((r == c) ? 1.f : 0.f) + pk[cc]);
    }
}

// ------- main: dense reads + nt full-line writes, raw barriers -------
// block = 16 rows x tile-pair pr. 4 waves (tw, hw). inbuf 2x8KB swizzled;
// outbuf 16KB [16 rows][256 f32] linear.
__global__ __launch_bounds__(256, 4)
void gemm_kernel(const float* __restrict__ x,
                 const unsigned short* __restrict__ mt,
                 float* __restrict__ out,
                 int nchunks) {
    __shared__ __align__(16) char  inbuf[2][8192];
    __shared__ __align__(16) float outbuf[16 * 256];

    const int tid  = threadIdx.x;
    const int pr   = blockIdx.x & 3;        // tile pair 0..3
    const int bc   = blockIdx.x >> 2;       // 0..255
    const int cs   = gridDim.x >> 2;        // chunk stride
    const int lane = tid & 63, w = tid >> 6;
    const int tw = w >> 1, hw = w & 1;      // tile-in-pair, n-half
    const int twg = pr * 2 + tw;
    const int ln = lane & 15, lk = lane >> 4;

    // M^T fragments for (tile twg, n-half hw): 64 VGPR, persistent
    bf16x8 a[4][4];
    {
        const unsigned short* mtt = mt + twg * 16384;
#pragma unroll
        for (int fn = 0; fn < 4; ++fn)
#pragma unroll
            for (int ks = 0; ks < 4; ++ks)
                a[fn][ks] = *(const bf16x8*)(mtt + (hw*64 + fn*16 + ln)*128
                                                 + ks*32 + lk*8);
    }

    // staging map: thread = (row sr, seg 0..15), INTERLEAVED dense loads:
    // instr l covers f32 [l*64 + seg*4, +4) of this row's 256-f32 block.
    const int sr  = tid >> 4, seg = tid & 15;
    const size_t gb  = (size_t)pr * 128 + seg * 4;   // f32 col of instr 0
    const int    swz = (sr & 7) << 4;

    float4 L[4];
#define ISSUE(cc) { \
        const float* xr = x + ((size_t)(cc) * 16 + sr) * 1024 + gb; \
        L[0] = *(const float4*)(xr);       L[1] = *(const float4*)(xr + 64); \
        L[2] = *(const float4*)(xr + 512); L[3] = *(const float4*)(xr + 576); }

    int c = bc;
    if (c < nchunks) ISSUE(c)

    int cur = 0;
    while (c < nchunks) {
        // ---- pack chunk c -> inbuf[cur]: 4x 8B swizzled writes ----
        {
#pragma unroll
            for (int l = 0; l < 4; ++l) {
                short4 h;
                h.x = hwbf(L[l].x); h.y = hwbf(L[l].y);
                h.z = hwbf(L[l].z); h.w = hwbf(L[l].w);
                // k = l*64 + seg*4  -> byte = sr*512 + k*2
                const int byte = (sr * 512 + l * 128 + seg * 8) ^ swz;
                *(short4*)(inbuf[cur] + byte) = h;
            }
        }
        // barrier A: LDS visibility only — no vmcnt drain
        asm volatile("s_waitcnt lgkmcnt(0)" ::: "memory");
        __builtin_amdgcn_s_barrier();
        __builtin_amdgcn_sched_barrier(0);

        // ---- prefetch next chunk (never drained by anything) ----
        const int cn = c + cs;
        if (cn < nchunks) ISSUE(cn)

        // ---- compute from inbuf[cur]: 16 MFMA ----
        f32x4 acc[4];
#pragma unroll
        for (int fn = 0; fn < 4; ++fn) acc[fn] = (f32x4)(0.f);
#pragma unroll
        for (int ks = 0; ks < 4; ++ks) {
            const int col = ((ks < 2) ? tw * 64 + ks * 32
                                      : 128 + tw * 64 + (ks - 2) * 32) + lk * 8;
            const bf16x8 bx = *(const bf16x8*)(inbuf[cur]
                                + ((ln * 512 + col * 2) ^ ((ln & 7) << 4)));
#pragma unroll
            for (int fn = 0; fn < 4; ++fn)
                acc[fn] = __builtin_amdgcn_mfma_f32_16x16x32_bf16(
                    a[fn][ks], bx, acc[fn], 0, 0, 0);
        }

        // ---- acc -> outbuf (chunk-local col m = tw*64+fn*16+lk*4+hw*128) ----
#pragma unroll
        for (int fn = 0; fn < 4; ++fn) {
            const int m = tw * 64 + fn * 16 + lk * 4 + hw * 128;
            *(f32x4*)(outbuf + ln * 256 + m) = acc[fn];
        }
        // barrier B: LDS visibility only
        asm volatile("s_waitcnt lgkmcnt(0)" ::: "memory");
        __builtin_amdgcn_s_barrier();
        __builtin_amdgcn_sched_barrier(0);

        // ---- writeback: 256B-contiguous nt per instruction (full lines) ----
        {
            float* orow = out + ((size_t)c * 16 + sr) * 1024;
#pragma unroll
            for (int l = 0; l < 4; ++l) {
                const int m2 = seg * 4 + l * 64;     // chunk-local f32 col
                const int gcol = (m2 < 128) ? (int)(pr * 128 + m2)
                                            : (int)(512 + pr * 128 + (m2 - 128));
                const f32x4 v = *(const f32x4*)(outbuf + sr * 256 + m2);
                __builtin_nontemporal_store(v, (f32x4*)(orow + gcol));
            }
        }

        cur ^= 1;
        c = cn;
    }
#undef ISSUE
}

extern "C" void kernel_launch(void* const* d_in, const int* in_sizes, int n_in,
                              void* d_out, int out_size, void* d_ws, size_t ws_size,
                              hipStream_t stream) {
    const float* x    = (const float*)d_in[0];
    const float4* phi = (const float4*)d_in[1];
    const float4* psi = (const float4*)d_in[2];
    unsigned short* mt = (unsigned short*)d_ws;    // 8*128*128 bf16 = 256KB
    float* out = (float*)d_out;

    const int rows    = in_sizes[0] / 1024;        // 65536
    const int nchunks = rows / 16;                 // 4096
    const int blocks  = 4 * 256;                   // 4 tile-pairs x 256

    prep_kernel<<<8, 256, 0, stream>>>(phi, psi, mt);
    gemm_kernel<<<blocks, 256, 0, stream>>>(x, mt, out, nchunks);
}